// Round 1
// baseline (502.562 us; speedup 1.0000x reference)
//
#include <hip/hip_runtime.h>

// PointConv: B=4, N=16384, K=32, F=64
// out[p,f] = sum_k ( lrelu(rel(p,k) @ W1 + b1) @ W2 + b2 )[f] * x[idx[p,k], f]
//
// Round 6: occupancy push. Counters showed all pipes idle (Mfma 8.5%, VALU 34%,
// HBM 17%) with OccupancyPercent ~20% (~2 waves/SIMD) -> latency-bound.
// The register footprint (acc 32 + xv 32 + bfrag 32 + pipeline state) was the
// occupancy cap. Changes vs round 5:
//  - bfrag evicted from registers: W2 fragments re-read from the conflict-free
//    LDS layout w2f[hf][t][c][m][j] inside the MFMA loop (8 ds_read_b128/point,
//    hidden under VALU/MFMA; LDS pipe was idle)
//  - __launch_bounds__(256, 5): cap ~102 regs -> 5 waves/SIMD target
// Everything else (scalar rowp idx loads, f16 packed h, f-interleaved tiles,
// b2-folded acc init, 1-deep rel_pos prefetch) unchanged.

#define NPTS   16384
#define KNB    32
#define F      64
#define BATCH  4
#define LOG2N  14
#define WPTS   8

typedef _Float16 h2     __attribute__((ext_vector_type(2)));
typedef _Float16 h8     __attribute__((ext_vector_type(8)));
typedef float    f32x16 __attribute__((ext_vector_type(16)));

__global__ __launch_bounds__(256, 5) void pointconv_mfma(
    const float* __restrict__ x,
    const float* __restrict__ pos,
    const int*   __restrict__ idx,
    const float* __restrict__ W1,
    const float* __restrict__ b1,
    const float* __restrict__ W2,
    const float* __restrict__ b2,
    float*       __restrict__ out)
{
    // w1p[g/2] = {wx,wx', wy,wy', wz,wz', b1,b1'} for g-pair (f16)
    __shared__ __align__(16) _Float16 w1p[32][8];
    // w2f[hf][t][c][m][j] = f16(W2[16t+8hf+j][2m+c]) — fragment-ordered,
    // lanes read consecutive 16B blocks -> conflict-free ds_read_b128
    __shared__ __align__(16) _Float16 w2f[2][4][2][32][8];

    const int tid = threadIdx.x;
    if (tid < 32) {
        const int g = 2 * tid;
        w1p[tid][0] = (_Float16)W1[0 * F + g]; w1p[tid][1] = (_Float16)W1[0 * F + g + 1];
        w1p[tid][2] = (_Float16)W1[1 * F + g]; w1p[tid][3] = (_Float16)W1[1 * F + g + 1];
        w1p[tid][4] = (_Float16)W1[2 * F + g]; w1p[tid][5] = (_Float16)W1[2 * F + g + 1];
        w1p[tid][6] = (_Float16)b1[g];         w1p[tid][7] = (_Float16)b1[g + 1];
    }
#pragma unroll
    for (int r = 0; r < 16; ++r) {             // 4096 elems, coalesced global read
        const int e = r * 256 + tid;           // e = g*64 + f
        const int g = e >> 6, f = e & 63;
        w2f[(g >> 3) & 1][g >> 4][f & 1][f >> 1][g & 7] = (_Float16)W2[e];
    }
    __syncthreads();

    const int lane = tid & 63;
    const int wv   = tid >> 6;
    const int m    = lane & 31;   // MFMA row (neighbor slot) / f-pair index
    const int hf   = lane >> 5;   // k-half of A/B fragments

    const float2 b2v = *(const float2*)(b2 + 2 * m);

    const int p0   = (blockIdx.x * 4 + wv) * WPTS;
    const int p0_s = __builtin_amdgcn_readfirstlane(p0);
    const int base = (p0_s >> LOG2N) << LOG2N;                     // b*N
    const float* __restrict__ xb2 = x + (size_t)base * F + 2 * m;  // lane gather base

    // ---- prologue: rel_pos for point i=0 (lane owns neighbor m) ----
    float rx, ry, rz;
    {
        const int jm = idx[p0_s * KNB + m];
        const int nr = base + jm;
        rx = pos[p0_s * 3 + 0] - pos[nr * 3 + 0];
        ry = pos[p0_s * 3 + 1] - pos[nr * 3 + 1];
        rz = pos[p0_s * 3 + 2] - pos[nr * 3 + 2];
    }

    const h2 c01 = { (_Float16)0.1f, (_Float16)0.1f };

#pragma unroll 1
    for (int i = 0; i < WPTS; ++i) {
        const int p_s = p0_s + i;                       // wave-uniform (SGPR)
        const int* __restrict__ rowp = idx + (size_t)p_s * KNB;

        // ---- x-gather: rows via scalar loads, one float2 per reg ----
        float2 xv[16];
#pragma unroll
        for (int reg = 0; reg < 16; ++reg) {
            const int rA  = (reg & 3) + ((reg >> 2) << 3);
            const int jlo = rowp[rA];                   // s_load (uniform)
            const int jhi = rowp[rA + 4];               // s_load (uniform)
            const int jk  = hf ? jhi : jlo;             // v_cndmask
            xv[reg] = *(const float2*)(xb2 + (size_t)jk * F);
        }

        // ---- prefetch next point's rel_pos (hidden under MFMA phase) ----
        float rxn = 0.f, ryn = 0.f, rzn = 0.f;
        if (i + 1 < WPTS) {
            const int jmn = idx[(p_s + 1) * KNB + m];
            const int nr  = base + jmn;
            rxn = pos[(p_s + 1) * 3 + 0] - pos[nr * 3 + 0];
            ryn = pos[(p_s + 1) * 3 + 1] - pos[nr * 3 + 1];
            rzn = pos[(p_s + 1) * 3 + 2] - pos[nr * 3 + 2];
        }

        // ---- h in packed f16 A-layout + MFMA (acc preloaded with b2) ----
        f32x16 acc0, acc1;
#pragma unroll
        for (int r = 0; r < 16; ++r) { acc0[r] = b2v.x; acc1[r] = b2v.y; }

        const h2 rxp = { (_Float16)rx, (_Float16)rx };
        const h2 ryp = { (_Float16)ry, (_Float16)ry };
        const h2 rzp = { (_Float16)rz, (_Float16)rz };

#pragma unroll
        for (int t = 0; t < 4; ++t) {
            h8 af;
#pragma unroll
            for (int jj = 0; jj < 4; ++jj) {
                const int g2 = 8 * t + 4 * hf + jj;              // g-pair index
                const h8 w = *(const h8*)&w1p[g2][0];            // b128, 2 addrs/wave
                const h2 wx = __builtin_shufflevector(w, w, 0, 1);
                const h2 wy = __builtin_shufflevector(w, w, 2, 3);
                const h2 wz = __builtin_shufflevector(w, w, 4, 5);
                const h2 bb = __builtin_shufflevector(w, w, 6, 7);
                h2 hv = bb + rxp * wx;                           // v_pk_fma_f16
                hv = hv + ryp * wy;
                hv = hv + rzp * wz;
                hv = __builtin_elementwise_max(hv, hv * c01);    // leaky_relu(0.1)
                af[2 * jj]     = hv[0];
                af[2 * jj + 1] = hv[1];
            }
            // B fragments live in LDS, not registers: one conflict-free
            // ds_read_b128 each, re-read per point (frees 32 VGPRs)
            const h8 bf0 = *(const h8*)&w2f[hf][t][0][m][0];
            const h8 bf1 = *(const h8*)&w2f[hf][t][1][m][0];
            acc0 = __builtin_amdgcn_mfma_f32_32x32x16_f16(af, bf0, acc0, 0, 0, 0);
            acc1 = __builtin_amdgcn_mfma_f32_32x32x16_f16(af, bf1, acc1, 0, 0, 0);
        }

        // ---- epilogue: weighted sum over this half's 16 rows, merge halves ----
        float s0 = 0.f, s1 = 0.f;
#pragma unroll
        for (int reg = 0; reg < 16; ++reg) {
            s0 = fmaf(acc0[reg], xv[reg].x, s0);
            s1 = fmaf(acc1[reg], xv[reg].y, s1);
        }
        s0 += __shfl_xor(s0, 32);
        s1 += __shfl_xor(s1, 32);
        if (hf == 0)
            *(float2*)(out + (size_t)p_s * F + 2 * m) = make_float2(s0, s1);

        rx = rxn; ry = ryn; rz = rzn;
    }
}

extern "C" void kernel_launch(void* const* d_in, const int* in_sizes, int n_in,
                              void* d_out, int out_size, void* d_ws, size_t ws_size,
                              hipStream_t stream) {
    const float* x   = (const float*)d_in[0];
    const float* pos = (const float*)d_in[1];
    const int*   idx = (const int*)  d_in[2];
    const float* W1  = (const float*)d_in[3];
    const float* b1  = (const float*)d_in[4];
    const float* W2  = (const float*)d_in[5];
    const float* b2  = (const float*)d_in[6];
    float* out = (float*)d_out;

    dim3 grid((BATCH * NPTS) / (4 * WPTS));   // 4 waves/block, WPTS points/wave
    dim3 block(256);
    pointconv_mfma<<<grid, block, 0, stream>>>(x, pos, idx, W1, b1, W2, b2, out);
}

// Round 2
// 408.059 us; speedup vs baseline: 1.2316x; 1.2316x over previous
//
#include <hip/hip_runtime.h>

// PointConv: B=4, N=16384, K=32, F=64
// out[p,f] = sum_k ( lrelu(rel(p,k) @ W1 + b1) @ W2 + b2 )[f] * x[idx[p,k], f]
//
// Round 7: occupancy push, take 2. Round 6's __launch_bounds__(256,5) (~102-reg
// cap) spilled acc/xv to scratch: FETCH 89MB->1.38GB, WRITE 16->354MB, 5.4x
// regression. Occupancy itself DID rise 20->51% as predicted -> the lever is
// right, the cap was past the spill cliff (live set ~110-120 regs).
// Changes vs round 6:
//  - __launch_bounds__(256, 4): 128-reg budget, fits the ~115-reg live set
//    -> target 4 waves/SIMD (2x round 5) with zero spill
// Kept: bfrag-in-LDS (W2 fragments re-read via conflict-free ds_read_b128,
// frees 32 regs), scalar rowp idx loads, f16 packed h, f-interleaved tiles,
// b2-folded acc init, 1-deep rel_pos prefetch.
// Success criterion in counters: WRITE_SIZE back to ~16MB (no scratch).

#define NPTS   16384
#define KNB    32
#define F      64
#define BATCH  4
#define LOG2N  14
#define WPTS   8

typedef _Float16 h2     __attribute__((ext_vector_type(2)));
typedef _Float16 h8     __attribute__((ext_vector_type(8)));
typedef float    f32x16 __attribute__((ext_vector_type(16)));

__global__ __launch_bounds__(256, 4) void pointconv_mfma(
    const float* __restrict__ x,
    const float* __restrict__ pos,
    const int*   __restrict__ idx,
    const float* __restrict__ W1,
    const float* __restrict__ b1,
    const float* __restrict__ W2,
    const float* __restrict__ b2,
    float*       __restrict__ out)
{
    // w1p[g/2] = {wx,wx', wy,wy', wz,wz', b1,b1'} for g-pair (f16)
    __shared__ __align__(16) _Float16 w1p[32][8];
    // w2f[hf][t][c][m][j] = f16(W2[16t+8hf+j][2m+c]) — fragment-ordered,
    // lanes read consecutive 16B blocks -> conflict-free ds_read_b128
    __shared__ __align__(16) _Float16 w2f[2][4][2][32][8];

    const int tid = threadIdx.x;
    if (tid < 32) {
        const int g = 2 * tid;
        w1p[tid][0] = (_Float16)W1[0 * F + g]; w1p[tid][1] = (_Float16)W1[0 * F + g + 1];
        w1p[tid][2] = (_Float16)W1[1 * F + g]; w1p[tid][3] = (_Float16)W1[1 * F + g + 1];
        w1p[tid][4] = (_Float16)W1[2 * F + g]; w1p[tid][5] = (_Float16)W1[2 * F + g + 1];
        w1p[tid][6] = (_Float16)b1[g];         w1p[tid][7] = (_Float16)b1[g + 1];
    }
#pragma unroll
    for (int r = 0; r < 16; ++r) {             // 4096 elems, coalesced global read
        const int e = r * 256 + tid;           // e = g*64 + f
        const int g = e >> 6, f = e & 63;
        w2f[(g >> 3) & 1][g >> 4][f & 1][f >> 1][g & 7] = (_Float16)W2[e];
    }
    __syncthreads();

    const int lane = tid & 63;
    const int wv   = tid >> 6;
    const int m    = lane & 31;   // MFMA row (neighbor slot) / f-pair index
    const int hf   = lane >> 5;   // k-half of A/B fragments

    const float2 b2v = *(const float2*)(b2 + 2 * m);

    const int p0   = (blockIdx.x * 4 + wv) * WPTS;
    const int p0_s = __builtin_amdgcn_readfirstlane(p0);
    const int base = (p0_s >> LOG2N) << LOG2N;                     // b*N
    const float* __restrict__ xb2 = x + (size_t)base * F + 2 * m;  // lane gather base

    // ---- prologue: rel_pos for point i=0 (lane owns neighbor m) ----
    float rx, ry, rz;
    {
        const int jm = idx[p0_s * KNB + m];
        const int nr = base + jm;
        rx = pos[p0_s * 3 + 0] - pos[nr * 3 + 0];
        ry = pos[p0_s * 3 + 1] - pos[nr * 3 + 1];
        rz = pos[p0_s * 3 + 2] - pos[nr * 3 + 2];
    }

    const h2 c01 = { (_Float16)0.1f, (_Float16)0.1f };

#pragma unroll 1
    for (int i = 0; i < WPTS; ++i) {
        const int p_s = p0_s + i;                       // wave-uniform (SGPR)
        const int* __restrict__ rowp = idx + (size_t)p_s * KNB;

        // ---- x-gather: rows via scalar loads, one float2 per reg ----
        float2 xv[16];
#pragma unroll
        for (int reg = 0; reg < 16; ++reg) {
            const int rA  = (reg & 3) + ((reg >> 2) << 3);
            const int jlo = rowp[rA];                   // s_load (uniform)
            const int jhi = rowp[rA + 4];               // s_load (uniform)
            const int jk  = hf ? jhi : jlo;             // v_cndmask
            xv[reg] = *(const float2*)(xb2 + (size_t)jk * F);
        }

        // ---- prefetch next point's rel_pos (hidden under MFMA phase) ----
        float rxn = 0.f, ryn = 0.f, rzn = 0.f;
        if (i + 1 < WPTS) {
            const int jmn = idx[(p_s + 1) * KNB + m];
            const int nr  = base + jmn;
            rxn = pos[(p_s + 1) * 3 + 0] - pos[nr * 3 + 0];
            ryn = pos[(p_s + 1) * 3 + 1] - pos[nr * 3 + 1];
            rzn = pos[(p_s + 1) * 3 + 2] - pos[nr * 3 + 2];
        }

        // ---- h in packed f16 A-layout + MFMA (acc preloaded with b2) ----
        f32x16 acc0, acc1;
#pragma unroll
        for (int r = 0; r < 16; ++r) { acc0[r] = b2v.x; acc1[r] = b2v.y; }

        const h2 rxp = { (_Float16)rx, (_Float16)rx };
        const h2 ryp = { (_Float16)ry, (_Float16)ry };
        const h2 rzp = { (_Float16)rz, (_Float16)rz };

#pragma unroll
        for (int t = 0; t < 4; ++t) {
            h8 af;
#pragma unroll
            for (int jj = 0; jj < 4; ++jj) {
                const int g2 = 8 * t + 4 * hf + jj;              // g-pair index
                const h8 w = *(const h8*)&w1p[g2][0];            // b128, 2 addrs/wave
                const h2 wx = __builtin_shufflevector(w, w, 0, 1);
                const h2 wy = __builtin_shufflevector(w, w, 2, 3);
                const h2 wz = __builtin_shufflevector(w, w, 4, 5);
                const h2 bb = __builtin_shufflevector(w, w, 6, 7);
                h2 hv = bb + rxp * wx;                           // v_pk_fma_f16
                hv = hv + ryp * wy;
                hv = hv + rzp * wz;
                hv = __builtin_elementwise_max(hv, hv * c01);    // leaky_relu(0.1)
                af[2 * jj]     = hv[0];
                af[2 * jj + 1] = hv[1];
            }
            // B fragments live in LDS, not registers: one conflict-free
            // ds_read_b128 each, re-read per point (frees 32 VGPRs)
            const h8 bf0 = *(const h8*)&w2f[hf][t][0][m][0];
            const h8 bf1 = *(const h8*)&w2f[hf][t][1][m][0];
            acc0 = __builtin_amdgcn_mfma_f32_32x32x16_f16(af, bf0, acc0, 0, 0, 0);
            acc1 = __builtin_amdgcn_mfma_f32_32x32x16_f16(af, bf1, acc1, 0, 0, 0);
        }

        // ---- epilogue: weighted sum over this half's 16 rows, merge halves ----
        float s0 = 0.f, s1 = 0.f;
#pragma unroll
        for (int reg = 0; reg < 16; ++reg) {
            s0 = fmaf(acc0[reg], xv[reg].x, s0);
            s1 = fmaf(acc1[reg], xv[reg].y, s1);
        }
        s0 += __shfl_xor(s0, 32);
        s1 += __shfl_xor(s1, 32);
        if (hf == 0)
            *(float2*)(out + (size_t)p_s * F + 2 * m) = make_float2(s0, s1);

        rx = rxn; ry = ryn; rz = rzn;
    }
}

extern "C" void kernel_launch(void* const* d_in, const int* in_sizes, int n_in,
                              void* d_out, int out_size, void* d_ws, size_t ws_size,
                              hipStream_t stream) {
    const float* x   = (const float*)d_in[0];
    const float* pos = (const float*)d_in[1];
    const int*   idx = (const int*)  d_in[2];
    const float* W1  = (const float*)d_in[3];
    const float* b1  = (const float*)d_in[4];
    const float* W2  = (const float*)d_in[5];
    const float* b2  = (const float*)d_in[6];
    float* out = (float*)d_out;

    dim3 grid((BATCH * NPTS) / (4 * WPTS));   // 4 waves/block, WPTS points/wave
    dim3 block(256);
    pointconv_mfma<<<grid, block, 0, stream>>>(x, pos, idx, W1, b1, W2, b2, out);
}

// Round 3
// 138.342 us; speedup vs baseline: 3.6328x; 2.9496x over previous
//
#include <hip/hip_runtime.h>

// PointConv: B=4, N=16384, K=32, F=64
// out[p,f] = sum_k ( lrelu(rel(p,k) @ W1 + b1) @ W2 + b2 )[f] * x[idx[p,k], f]
//
// Round 8: revert the failed occupancy caps (r6: (256,5) spilled, r7: (256,4)
// still spilled — gfx950 occupancy steps at 64/128/256 regs and the ~140-180
// reg live set can't fit 128). Back to (256,2), attack latency instead:
// the per-point serial chain (idx s_load -> x-gather -> epilogue) was ~4800
// cyc/point vs ~400 cyc of issue work, with only 2 waves/SIMD to hide it.
//
// Changes vs round 5 (the 80 us baseline):
//  - 1-point software pipeline: point i+1's idx row is s_loaded during point
//    i's MFMA phase; point i+1's 32 x-gathers are issued right after point
//    i's MFMAs into a double-buffered xv (xvA/xvB, compile-time indexed);
//    point i's epilogue consumes gathers issued a full iteration earlier.
//  - single jlo/jhi SGPR set (live range: step1->step4 only, no overlap)
//  - bfrag stays in LDS (conflict-free ds_read_b128, frees 32 VGPRs of
//    steady-state pressure; keeps total ~170-190 << 256 budget)
// Success criteria: WRITE_SIZE ~16MB (no scratch), dur 80 -> 45-55 us.

#define NPTS   16384
#define KNB    32
#define F      64
#define BATCH  4
#define LOG2N  14
#define WPTS   8

typedef _Float16 h2     __attribute__((ext_vector_type(2)));
typedef _Float16 h8     __attribute__((ext_vector_type(8)));
typedef float    f32x16 __attribute__((ext_vector_type(16)));

__global__ __launch_bounds__(256, 2) void pointconv_mfma(
    const float* __restrict__ x,
    const float* __restrict__ pos,
    const int*   __restrict__ idx,
    const float* __restrict__ W1,
    const float* __restrict__ b1,
    const float* __restrict__ W2,
    const float* __restrict__ b2,
    float*       __restrict__ out)
{
    // w1p[g/2] = {wx,wx', wy,wy', wz,wz', b1,b1'} for g-pair (f16)
    __shared__ __align__(16) _Float16 w1p[32][8];
    // w2f[hf][t][c][m][j] = f16(W2[16t+8hf+j][2m+c]) — fragment-ordered,
    // lanes read consecutive 16B blocks -> conflict-free ds_read_b128
    __shared__ __align__(16) _Float16 w2f[2][4][2][32][8];

    const int tid = threadIdx.x;
    if (tid < 32) {
        const int g = 2 * tid;
        w1p[tid][0] = (_Float16)W1[0 * F + g]; w1p[tid][1] = (_Float16)W1[0 * F + g + 1];
        w1p[tid][2] = (_Float16)W1[1 * F + g]; w1p[tid][3] = (_Float16)W1[1 * F + g + 1];
        w1p[tid][4] = (_Float16)W1[2 * F + g]; w1p[tid][5] = (_Float16)W1[2 * F + g + 1];
        w1p[tid][6] = (_Float16)b1[g];         w1p[tid][7] = (_Float16)b1[g + 1];
    }
#pragma unroll
    for (int r = 0; r < 16; ++r) {             // 4096 elems, coalesced global read
        const int e = r * 256 + tid;           // e = g*64 + f
        const int g = e >> 6, f = e & 63;
        w2f[(g >> 3) & 1][g >> 4][f & 1][f >> 1][g & 7] = (_Float16)W2[e];
    }
    __syncthreads();

    const int lane = tid & 63;
    const int wv   = tid >> 6;
    const int m    = lane & 31;   // MFMA row (neighbor slot) / f-pair index
    const int hf   = lane >> 5;   // k-half of A/B fragments

    const float2 b2v = *(const float2*)(b2 + 2 * m);

    const int p0   = (blockIdx.x * 4 + wv) * WPTS;
    const int p0_s = __builtin_amdgcn_readfirstlane(p0);
    const int base = (p0_s >> LOG2N) << LOG2N;                     // b*N
    const float* __restrict__ xb2 = x + (size_t)base * F + 2 * m;  // lane gather base

    // single idx-row SGPR set: written in step (1) of iter i (row i+1),
    // consumed in step (4) of the same iter — no cross-iter live overlap
    int jlo[16], jhi[16];

    // ---- prologue: idx row + x-gather + rel_pos for point 0 ----
    {
        const int* __restrict__ rowp = idx + (size_t)p0_s * KNB;
#pragma unroll
        for (int reg = 0; reg < 16; ++reg) {
            const int rA = (reg & 3) + ((reg >> 2) << 3);
            jlo[reg] = rowp[rA];
            jhi[reg] = rowp[rA + 4];
        }
    }
    float2 xvA[16], xvB[16];
#pragma unroll
    for (int reg = 0; reg < 16; ++reg) {
        const int jk = hf ? jhi[reg] : jlo[reg];
        xvA[reg] = *(const float2*)(xb2 + (size_t)jk * F);
    }

    float rx, ry, rz;
    {
        const int jm = idx[p0_s * KNB + m];
        const int nr = base + jm;
        rx = pos[p0_s * 3 + 0] - pos[nr * 3 + 0];
        ry = pos[p0_s * 3 + 1] - pos[nr * 3 + 1];
        rz = pos[p0_s * 3 + 2] - pos[nr * 3 + 2];
    }

    const h2 c01 = { (_Float16)0.1f, (_Float16)0.1f };

    // XV_CUR: gathers issued one full iteration ago (latency hidden)
    // XV_NXT: gathers issued this iteration, consumed next
#define POINT_BODY(XV_CUR, XV_NXT, I)                                         \
    {                                                                         \
        const int p_s = p0_s + (I);                                           \
        const bool has_next = (I) + 1 < WPTS;                                 \
        /* (1) prefetch next point's idx row (s_loads, hidden under MFMA) */  \
        if (has_next) {                                                       \
            const int* __restrict__ rowp = idx + (size_t)(p_s + 1) * KNB;     \
            _Pragma("unroll")                                                 \
            for (int reg = 0; reg < 16; ++reg) {                              \
                const int rA = (reg & 3) + ((reg >> 2) << 3);                 \
                jlo[reg] = rowp[rA];                                          \
                jhi[reg] = rowp[rA + 4];                                      \
            }                                                                 \
        }                                                                     \
        /* (2) prefetch next point's rel_pos */                               \
        float rxn = 0.f, ryn = 0.f, rzn = 0.f;                                \
        if (has_next) {                                                       \
            const int jmn = idx[(p_s + 1) * KNB + m];                         \
            const int nr  = base + jmn;                                       \
            rxn = pos[(p_s + 1) * 3 + 0] - pos[nr * 3 + 0];                   \
            ryn = pos[(p_s + 1) * 3 + 1] - pos[nr * 3 + 1];                   \
            rzn = pos[(p_s + 1) * 3 + 2] - pos[nr * 3 + 2];                   \
        }                                                                     \
        /* (3) h in packed f16 + MFMA (acc preloaded with b2) */              \
        f32x16 acc0, acc1;                                                    \
        _Pragma("unroll")                                                     \
        for (int r = 0; r < 16; ++r) { acc0[r] = b2v.x; acc1[r] = b2v.y; }    \
        const h2 rxp = { (_Float16)rx, (_Float16)rx };                        \
        const h2 ryp = { (_Float16)ry, (_Float16)ry };                        \
        const h2 rzp = { (_Float16)rz, (_Float16)rz };                        \
        _Pragma("unroll")                                                     \
        for (int t = 0; t < 4; ++t) {                                         \
            h8 af;                                                            \
            _Pragma("unroll")                                                 \
            for (int jj = 0; jj < 4; ++jj) {                                  \
                const int g2 = 8 * t + 4 * hf + jj;                           \
                const h8 w = *(const h8*)&w1p[g2][0];                         \
                const h2 wx = __builtin_shufflevector(w, w, 0, 1);            \
                const h2 wy = __builtin_shufflevector(w, w, 2, 3);            \
                const h2 wz = __builtin_shufflevector(w, w, 4, 5);            \
                const h2 bb = __builtin_shufflevector(w, w, 6, 7);            \
                h2 hv = bb + rxp * wx;                                        \
                hv = hv + ryp * wy;                                           \
                hv = hv + rzp * wz;                                           \
                hv = __builtin_elementwise_max(hv, hv * c01);                 \
                af[2 * jj]     = hv[0];                                       \
                af[2 * jj + 1] = hv[1];                                       \
            }                                                                 \
            const h8 bf0 = *(const h8*)&w2f[hf][t][0][m][0];                  \
            const h8 bf1 = *(const h8*)&w2f[hf][t][1][m][0];                  \
            acc0 = __builtin_amdgcn_mfma_f32_32x32x16_f16(af, bf0, acc0, 0, 0, 0); \
            acc1 = __builtin_amdgcn_mfma_f32_32x32x16_f16(af, bf1, acc1, 0, 0, 0); \
        }                                                                     \
        /* (4) issue next point's x-gathers (consumed next iteration) */      \
        if (has_next) {                                                       \
            _Pragma("unroll")                                                 \
            for (int reg = 0; reg < 16; ++reg) {                              \
                const int jk = hf ? jhi[reg] : jlo[reg];                      \
                XV_NXT[reg] = *(const float2*)(xb2 + (size_t)jk * F);         \
            }                                                                 \
        }                                                                     \
        /* (5) epilogue: consume XV_CUR (issued one iteration ago) */         \
        float s0 = 0.f, s1 = 0.f;                                             \
        _Pragma("unroll")                                                     \
        for (int reg = 0; reg < 16; ++reg) {                                  \
            s0 = fmaf(acc0[reg], XV_CUR[reg].x, s0);                          \
            s1 = fmaf(acc1[reg], XV_CUR[reg].y, s1);                          \
        }                                                                     \
        s0 += __shfl_xor(s0, 32);                                             \
        s1 += __shfl_xor(s1, 32);                                             \
        if (hf == 0)                                                          \
            *(float2*)(out + (size_t)p_s * F + 2 * m) = make_float2(s0, s1);  \
        rx = rxn; ry = ryn; rz = rzn;                                         \
    }

#pragma unroll 1
    for (int io = 0; io < WPTS; io += 2) {
        POINT_BODY(xvA, xvB, io);
        POINT_BODY(xvB, xvA, io + 1);
    }
#undef POINT_BODY
}

extern "C" void kernel_launch(void* const* d_in, const int* in_sizes, int n_in,
                              void* d_out, int out_size, void* d_ws, size_t ws_size,
                              hipStream_t stream) {
    const float* x   = (const float*)d_in[0];
    const float* pos = (const float*)d_in[1];
    const int*   idx = (const int*)  d_in[2];
    const float* W1  = (const float*)d_in[3];
    const float* b1  = (const float*)d_in[4];
    const float* W2  = (const float*)d_in[5];
    const float* b2  = (const float*)d_in[6];
    float* out = (float*)d_out;

    dim3 grid((BATCH * NPTS) / (4 * WPTS));   // 4 waves/block, WPTS points/wave
    dim3 block(256);
    pointconv_mfma<<<grid, block, 0, stream>>>(x, pos, idx, W1, b1, W2, b2, out);
}